// Round 5
// baseline (627.634 us; speedup 1.0000x reference)
//
#include <hip/hip_runtime.h>
#include <hip/hip_bf16.h>

typedef __hip_bfloat16 bf16;
typedef __attribute__((ext_vector_type(8))) short bf16x8;
typedef __attribute__((ext_vector_type(4))) float f32x4;

#define S_LEN   2048
#define HIDDEN  5120
#define NHEADS  16
#define QLORA   1536
#define KVLORA  512
#define QKD     192
#define VD      128
#define QN      (NHEADS*QKD)          /* 3072 */
#define KVN     (NHEADS*(128+VD))     /* 4096 */
#define QCKN    2112                  /* 1536 qa | 512 ckv | 64 kpe */
#define SM_SCALE 0.07216878364870322f /* 192^-0.5 */

__device__ __forceinline__ f32x4 mfma16(bf16x8 a, bf16x8 b, f32x4 c) {
  return __builtin_amdgcn_mfma_f32_16x16x32_bf16(a, b, c, 0, 0, 0);
}
__device__ __forceinline__ void g2l16(const void* g, void* l) {
  __builtin_amdgcn_global_load_lds((const __attribute__((address_space(1))) void*)g,
                                   (__attribute__((address_space(3))) void*)l, 16, 0, 0);
}
__device__ __forceinline__ bf16x8 ld8(const bf16* p) { return *(const bf16x8*)p; }

// -------- init: zero split-K accumulators + out_hidden = hs*0.125 ----------
__global__ void init_k(float4* __restrict__ qa_ckv, int n_qa,
                       float4* __restrict__ q_f, int n_q,
                       const float4* __restrict__ hs, float4* __restrict__ oh, int n_h)
{
  int i = blockIdx.x * 256 + threadIdx.x;
  if (i < n_qa) { qa_ckv[i] = (float4){0.f, 0.f, 0.f, 0.f}; return; }
  if ((i -= n_qa) < n_q) { q_f[i] = (float4){0.f, 0.f, 0.f, 0.f}; return; }
  if ((i -= n_q) < n_h) {
    float4 v = hs[i];
    v.x *= 0.125f; v.y *= 0.125f; v.z *= 0.125f; v.w *= 0.125f;
    oh[i] = v;
  }
}

// ---------------- fused fp32 -> bf16 cast over 5 weight segments ----------------
__global__ void cvt_multi(const float* s0, bf16* d0, int n0,
                          const float* s1, bf16* d1, int n1,
                          const float* s2, bf16* d2, int n2,
                          const float* s3, bf16* d3, int n3,
                          const float* s4, bf16* d4, int n4s)
{
  int i = blockIdx.x * 256 + threadIdx.x;
  const float* s; bf16* d;
  if (i < n0) { s = s0; d = d0; }
  else if ((i -= n0) < n1) { s = s1; d = d1; }
  else if ((i -= n1) < n2) { s = s2; d = d2; }
  else if ((i -= n2) < n3) { s = s3; d = d3; }
  else if ((i -= n3) < n4s) { s = s4; d = d4; }
  else return;
  const float4 v = ((const float4*)s)[i];
  union { bf16 b[4]; unsigned long long u; } pk;
  pk.b[0] = __float2bfloat16(v.x);
  pk.b[1] = __float2bfloat16(v.y);
  pk.b[2] = __float2bfloat16(v.z);
  pk.b[3] = __float2bfloat16(v.w);
  *(unsigned long long*)(d + (size_t)i * 4) = pk.u;
}

// ---------------- RMSNorm (fp32 in, bf16 out), one block per row ----------------
__global__ void rmsnorm_k(const float* __restrict__ in, int istride, int C,
                          const float* __restrict__ w,
                          bf16* __restrict__ out, int ostride)
{
  const int row = blockIdx.x;
  const float* x = in + (size_t)row * istride;
  float ss = 0.f;
  for (int c = threadIdx.x; c < C; c += 256) { float v = x[c]; ss += v * v; }
  #pragma unroll
  for (int m = 32; m >= 1; m >>= 1) ss += __shfl_xor(ss, m, 64);
  __shared__ float red[4];
  if ((threadIdx.x & 63) == 0) red[threadIdx.x >> 6] = ss;
  __syncthreads();
  ss = red[0] + red[1] + red[2] + red[3];
  const float sc = rsqrtf(ss / (float)C + 1e-6f);
  bf16* o = out + (size_t)row * ostride;
  for (int c = threadIdx.x; c < C; c += 256)
    o[c] = __float2bfloat16(x[c] * sc * w[c]);
}

// ---------------- NT GEMM, BK=64: C[M,N] (+)= A[M,K]*Bt[N,K]^T over K-chunk ----
// 128x128 tile, BK=64 (32 MFMA per barrier pair -> half the vmcnt(0) drains of
// BK=32), 4 waves each 64x64, global_load_lds width 16. LDS 32 KB.
// Split-K via blockIdx.z (klen multiple of 64), ATOMIC accumulate.
template<bool CLAMPN, bool ATOMIC>
__global__ __launch_bounds__(256, 2)
void gemm_nt(const bf16* __restrict__ A, const bf16* __restrict__ Bt,
             float* __restrict__ C, int M, int N, int lda, int klen)
{
  __shared__ bf16 As[2 * 128 * 32];   // chunk-major: [c][row][32]
  __shared__ bf16 Bs[2 * 128 * 32];
  const int tid = threadIdx.x;
  const int wave = tid >> 6;
  const int lane = tid & 63;
  const int l15 = lane & 15, quad = lane >> 4;
  const int bm = blockIdx.x * 128, bn = blockIdx.y * 128;
  const int kbase = blockIdx.z * klen;
  const int wm = (wave >> 1) * 64, wn = (wave & 1) * 64;

  const int srow = tid >> 2;        // 0..63
  const int scol = (tid & 3) * 8;   // 0,8,16,24
  const bf16* Ag0 = A + (size_t)(bm + srow) * lda + kbase + scol;
  const bf16* Ag1 = A + (size_t)(bm + 64 + srow) * lda + kbase + scol;
  int bn0 = bn + srow, bn1 = bn + 64 + srow;
  if (CLAMPN) { bn0 = min(bn0, N - 1); bn1 = min(bn1, N - 1); }
  const bf16* Bg0 = Bt + (size_t)bn0 * lda + kbase + scol;
  const bf16* Bg1 = Bt + (size_t)bn1 * lda + kbase + scol;

  char* AsW = (char*)As + wave * 1024;   // + c*8192 + half*4096 (+lane*16 by HW)
  char* BsW = (char*)Bs + wave * 1024;

  f32x4 acc[4][4];
  #pragma unroll
  for (int i = 0; i < 4; i++)
    #pragma unroll
    for (int j = 0; j < 4; j++) acc[i][j] = (f32x4){0.f, 0.f, 0.f, 0.f};

  const int nk = klen >> 6;
  for (int kt = 0; kt < nk; ++kt) {
    const int k0 = kt << 6;
    #pragma unroll
    for (int c = 0; c < 2; ++c) {
      g2l16(Ag0 + k0 + c * 32, AsW + c * 8192);
      g2l16(Ag1 + k0 + c * 32, AsW + c * 8192 + 4096);
      g2l16(Bg0 + k0 + c * 32, BsW + c * 8192);
      g2l16(Bg1 + k0 + c * 32, BsW + c * 8192 + 4096);
    }
    __syncthreads();
    #pragma unroll
    for (int c = 0; c < 2; ++c) {
      bf16x8 af[4], bfr[4];
      #pragma unroll
      for (int i = 0; i < 4; i++)
        af[i] = ld8(As + c * 4096 + (wm + i * 16 + l15) * 32 + quad * 8);
      #pragma unroll
      for (int j = 0; j < 4; j++)
        bfr[j] = ld8(Bs + c * 4096 + (wn + j * 16 + l15) * 32 + quad * 8);
      #pragma unroll
      for (int i = 0; i < 4; i++)
        #pragma unroll
        for (int j = 0; j < 4; j++)
          acc[i][j] = mfma16(af[i], bfr[j], acc[i][j]);
    }
    __syncthreads();
  }

  #pragma unroll
  for (int i = 0; i < 4; i++)
    #pragma unroll
    for (int j = 0; j < 4; j++) {
      const int row = bm + wm + i * 16 + quad * 4;
      const int col = bn + wn + j * 16 + l15;
      if (!CLAMPN || col < N) {
        #pragma unroll
        for (int r = 0; r < 4; r++) {
          const float v = acc[i][j][r];
          const size_t idx = (size_t)(row + r) * N + col;
          if (ATOMIC) unsafeAtomicAdd(&C[idx], v);
          else        C[idx] = v;
        }
      }
    }
}

// ---------------- RoPE + assemble q/k (bf16 for attn, fp32 k out) ----------------
__global__ void rope_assemble_k(
    const float* __restrict__ q,      // [S, 3072]
    const float* __restrict__ qackv,  // [S, 2112] (kpe at col 2048)
    const float* __restrict__ kv,     // [S, 4096]
    const int*   __restrict__ pos,    // [S]
    float* __restrict__ k_out,        // [16,S,192]
    bf16*  __restrict__ q_bf,         // [16,S,192]
    bf16*  __restrict__ k_bf)         // [16,S,192]
{
  const int s = blockIdx.x;
  const int t = threadIdx.x;
  __shared__ float cs[32], sn[32], kpe[64];
  const float p = (float)pos[s];
  if (t < 32) {
    const float inv = powf(10000.0f, -((float)(2 * t)) / 64.0f);
    const float f = p * inv;
    float si, c;
    sincosf(f, &si, &c);
    cs[t] = c; sn[t] = si;
    const float r0v = qackv[(size_t)s * QCKN + 2048 + 2 * t];
    const float r1v = qackv[(size_t)s * QCKN + 2048 + 2 * t + 1];
    kpe[t]      = r0v * c - r1v * si;
    kpe[32 + t] = r1v * c + r0v * si;
  }
  __syncthreads();
  for (int i = t; i < NHEADS * 128; i += 256) {
    const int h = i >> 7, d = i & 127;
    const size_t o = ((size_t)h * S_LEN + s) * QKD + d;
    const float kn = kv[(size_t)s * KVN + h * 256 + d];
    k_out[o] = kn;
    k_bf[o] = __float2bfloat16(kn);
    q_bf[o] = __float2bfloat16(q[(size_t)s * QN + h * QKD + d]);
  }
  for (int i = t; i < NHEADS * 32; i += 256) {
    const int h = i >> 5, jj = i & 31;
    const float r0v = q[(size_t)s * QN + h * QKD + 128 + 2 * jj];
    const float r1v = q[(size_t)s * QN + h * QKD + 128 + 2 * jj + 1];
    const float c = cs[jj], si = sn[jj];
    const size_t o = ((size_t)h * S_LEN + s) * QKD + 128;
    q_bf[o + jj]      = __float2bfloat16(r0v * c - r1v * si);
    q_bf[o + 32 + jj] = __float2bfloat16(r1v * c + r0v * si);
  }
  for (int i = t; i < NHEADS * 64; i += 256) {
    const int h = i >> 6, jj = i & 63;
    const float v = kpe[jj];
    const size_t o = ((size_t)h * S_LEN + s) * QKD + 128 + jj;
    k_out[o] = v;
    k_bf[o] = __float2bfloat16(v);
  }
}

// ---------------- V: fp32 out + bf16 transpose [16][128][2048] ----------------
__global__ void v_transpose_k(const float* __restrict__ kv,
                              float* __restrict__ v_out,
                              bf16* __restrict__ vt_bf)
{
  const int h = blockIdx.x, st = blockIdx.y, dt = blockIdx.z;
  __shared__ float tile[32][33];
  const int tx = threadIdx.x & 31;
  const int ty = (threadIdx.x >> 5) * 4;
  const int s0 = st * 32, d0 = dt * 32;
  #pragma unroll
  for (int r = 0; r < 4; r++) {
    const int sl = ty + r;
    const float v = kv[(size_t)(s0 + sl) * KVN + h * 256 + 128 + d0 + tx];
    v_out[((size_t)h * S_LEN + s0 + sl) * VD + d0 + tx] = v;
    tile[sl][tx] = v;
  }
  __syncthreads();
  #pragma unroll
  for (int r = 0; r < 4; r++) {
    const int dl = ty + r;
    vt_bf[((size_t)h * VD + d0 + dl) * S_LEN + s0 + tx] = __float2bfloat16(tile[tx][dl]);
  }
}

// ---------------- causal flash attention (v4) ----------------
__global__ __launch_bounds__(256, 3)
void attn_k(const bf16* __restrict__ qb, const bf16* __restrict__ kb,
            const bf16* __restrict__ vt, bf16* __restrict__ aout)
{
  const int head = blockIdx.y;
  const int qt = (head < 8) ? blockIdx.x : (gridDim.x - 1 - blockIdx.x);
  const int wave = threadIdx.x >> 6, lane = threadIdx.x & 63;
  const int l15 = lane & 15, quad = lane >> 4;
  const int r0 = qt * 64 + wave * 16;

  const bf16* qh = qb + (size_t)head * S_LEN * QKD;
  const bf16* kh = kb + (size_t)head * S_LEN * QKD;
  const bf16* vh = vt + (size_t)head * VD * S_LEN;

  __shared__ bf16 Ks[6 * 64 * 32];      // 24 KB, chunk-major [6][64][32]
  __shared__ bf16 Vs[128 * 72];         // 18 KB, [128 d][64 s], row pad 72
  __shared__ bf16 Plds[4][16][72];      // 9 KB, per-wave

  const int tid = threadIdx.x;
  const int srow = wave * 16 + (lane >> 2);
  const int scol = (lane & 3) * 8;
  const bf16* ksrc = kh + (size_t)srow * QKD + scol;
  bf16* kdst = Ks + srow * 32 + scol;
  const int vrow = tid >> 1;
  const int vcol = (tid & 1) * 32;
  const bf16* vsrc = vh + (size_t)vrow * S_LEN + vcol;
  bf16* vdst = Vs + vrow * 72 + vcol;

  bf16x8 qf[6];
  #pragma unroll
  for (int c = 0; c < 6; ++c)
    qf[c] = ld8(qh + (size_t)(r0 + l15) * QKD + c * 32 + quad * 8);

  f32x4 O[8];
  #pragma unroll
  for (int d = 0; d < 8; ++d) O[d] = (f32x4){0.f, 0.f, 0.f, 0.f};
  float mrow[4] = {-1e30f, -1e30f, -1e30f, -1e30f};
  float lrow[4] = {0.f, 0.f, 0.f, 0.f};

  bf16x8 kreg[6], vreg[4];
  #pragma unroll
  for (int c = 0; c < 6; ++c) kreg[c] = ld8(ksrc + c * 32);
  #pragma unroll
  for (int c = 0; c < 4; ++c) vreg[c] = ld8(vsrc + c * 8);

  for (int j = 0; j <= qt; ++j) {
    __syncthreads();
    #pragma unroll
    for (int c = 0; c < 6; ++c) *(bf16x8*)(kdst + c * 2048) = kreg[c];
    #pragma unroll
    for (int c = 0; c < 4; ++c) *(bf16x8*)(vdst + c * 8) = vreg[c];
    __syncthreads();
    if (j < qt) {
      const bf16* src = ksrc + (size_t)(j + 1) * 64 * QKD;
      #pragma unroll
      for (int c = 0; c < 6; ++c) kreg[c] = ld8(src + c * 32);
      const bf16* vs2 = vsrc + (size_t)(j + 1) * 64;
      #pragma unroll
      for (int c = 0; c < 4; ++c) vreg[c] = ld8(vs2 + c * 8);
    }
    const int kc = j * 64;

    f32x4 S[4];
    #pragma unroll
    for (int nt = 0; nt < 4; ++nt) S[nt] = (f32x4){0.f, 0.f, 0.f, 0.f};
    #pragma unroll
    for (int c = 0; c < 6; ++c) {
      #pragma unroll
      for (int nt = 0; nt < 4; ++nt) {
        const bf16x8 kf = ld8(Ks + c * 2048 + (nt * 16 + l15) * 32 + quad * 8);
        S[nt] = mfma16(qf[c], kf, S[nt]);
      }
    }

    float mnew[4] = {-1e30f, -1e30f, -1e30f, -1e30f};
    if (j == qt) {
      #pragma unroll
      for (int nt = 0; nt < 4; ++nt) {
        const int col = kc + nt * 16 + l15;
        #pragma unroll
        for (int r = 0; r < 4; r++) {
          const int row = r0 + quad * 4 + r;
          const float v = (col <= row) ? S[nt][r] * SM_SCALE : -1e30f;
          S[nt][r] = v;
          mnew[r] = fmaxf(mnew[r], v);
        }
      }
    } else {
      #pragma unroll
      for (int nt = 0; nt < 4; ++nt)
        #pragma unroll
        for (int r = 0; r < 4; r++) {
          const float v = S[nt][r] * SM_SCALE;
          S[nt][r] = v;
          mnew[r] = fmaxf(mnew[r], v);
        }
    }
    #pragma unroll
    for (int m = 8; m >= 1; m >>= 1)
      #pragma unroll
      for (int r = 0; r < 4; r++)
        mnew[r] = fmaxf(mnew[r], __shfl_xor(mnew[r], m, 64));
    float alpha[4], ladd[4] = {0.f, 0.f, 0.f, 0.f};
    #pragma unroll
    for (int r = 0; r < 4; r++) {
      const float mi = fmaxf(mrow[r], mnew[r]);
      alpha[r] = __expf(mrow[r] - mi);
      mrow[r] = mi;
    }
    #pragma unroll
    for (int nt = 0; nt < 4; ++nt)
      #pragma unroll
      for (int r = 0; r < 4; r++) {
        const float pv = __expf(S[nt][r] - mrow[r]);
        S[nt][r] = pv;
        ladd[r] += pv;
      }
    #pragma unroll
    for (int m = 8; m >= 1; m >>= 1)
      #pragma unroll
      for (int r = 0; r < 4; r++) ladd[r] += __shfl_xor(ladd[r], m, 64);
    #pragma unroll
    for (int r = 0; r < 4; r++) lrow[r] = lrow[r] * alpha[r] + ladd[r];
    #pragma unroll
    for (int d = 0; d < 8; ++d)
      #pragma unroll
      for (int r = 0; r < 4; r++) O[d][r] *= alpha[r];

    #pragma unroll
    for (int nt = 0; nt < 4; ++nt)
      #pragma unroll
      for (int r = 0; r < 4; r++)
        Plds[wave][quad * 4 + r][nt * 16 + l15] = __float2bfloat16(S[nt][r]);

    #pragma unroll
    for (int kt = 0; kt < 2; ++kt) {
      const bf16x8 pf = ld8(&Plds[wave][l15][kt * 32 + quad * 8]);
      #pragma unroll
      for (int dt = 0; dt < 8; ++dt) {
        const bf16x8 vf = ld8(Vs + (dt * 16 + l15) * 72 + kt * 32 + quad * 8);
        O[dt] = mfma16(pf, vf, O[dt]);
      }
    }
  }

  #pragma unroll
  for (int dt = 0; dt < 8; ++dt) {
    const int col = head * VD + dt * 16 + l15;
    #pragma unroll
    for (int r = 0; r < 4; r++) {
      const int row = r0 + quad * 4 + r;
      aout[(size_t)row * (NHEADS * VD) + col] = __float2bfloat16(O[dt][r] / lrow[r]);
    }
  }
}

// ---------------- host orchestration ----------------
extern "C" void kernel_launch(void* const* d_in, const int* in_sizes, int n_in,
                              void* d_out, int out_size, void* d_ws, size_t ws_size,
                              hipStream_t stream)
{
  const float* hs      = (const float*)d_in[0];
  const int*   pos     = (const int*)  d_in[1];
  const float* ln_w    = (const float*)d_in[3];
  const float* wq_a    = (const float*)d_in[4];
  const float* q_a_ln  = (const float*)d_in[5];
  const float* wq_b    = (const float*)d_in[6];
  const float* wkv_a   = (const float*)d_in[7];
  const float* kv_a_ln = (const float*)d_in[8];
  const float* wkv_b   = (const float*)d_in[9];
  const float* wo      = (const float*)d_in[10];

  float* out_hidden = (float*)d_out;
  float* out_k = out_hidden + (size_t)S_LEN * HIDDEN;
  float* out_v = out_k + (size_t)NHEADS * S_LEN * QKD;

  char* ws = (char*)d_ws;
  size_t off = 0;
  auto alloc = [&](size_t bytes) { char* p = ws + off; off += (bytes + 255) & ~255ULL; return p; };

  bf16* h_b     = (bf16*)alloc((size_t)S_LEN * HIDDEN * 2);
  bf16* w1_b    = (bf16*)alloc((size_t)QCKN * HIDDEN * 2);   // [qa(1536)|kva(576)][5120]
  bf16* wqb_b   = (bf16*)alloc((size_t)QN * QLORA * 2);
  bf16* wkvb_b  = (bf16*)alloc((size_t)KVN * KVLORA * 2);
  bf16* wo_b    = (bf16*)alloc((size_t)HIDDEN * (NHEADS * VD) * 2);
  float* qa_ckv = (float*)alloc((size_t)S_LEN * QCKN * 4);   // fp32, zero-init (atomics)
  float* q_f    = (float*)alloc((size_t)S_LEN * QN * 4);     // fp32, zero-init (atomics)
  bf16* qa_n    = (bf16*)alloc((size_t)S_LEN * QLORA * 2);
  bf16* ckv_n   = (bf16*)alloc((size_t)S_LEN * KVLORA * 2);
  float* kv_f   = (float*)alloc((size_t)S_LEN * KVN * 4);
  bf16* q_bf    = (bf16*)alloc((size_t)NHEADS * S_LEN * QKD * 2);
  bf16* k_bf    = (bf16*)alloc((size_t)NHEADS * S_LEN * QKD * 2);
  bf16* vt_bf   = (bf16*)alloc((size_t)NHEADS * VD * S_LEN * 2);
  bf16* attn_b  = (bf16*)alloc((size_t)S_LEN * (NHEADS * VD) * 2);

  // init: zero qa_ckv & q_f, out_hidden = hs * 0.125 (residual pre-store)
  {
    const int n_qa = (int)((size_t)S_LEN * QCKN / 4);
    const int n_q  = (int)((size_t)S_LEN * QN / 4);
    const int n_h  = (int)((size_t)S_LEN * HIDDEN / 4);
    const int tot = n_qa + n_q + n_h;
    init_k<<<(tot + 255) / 256, 256, 0, stream>>>(
        (float4*)qa_ckv, n_qa, (float4*)q_f, n_q,
        (const float4*)hs, (float4*)out_hidden, n_h);
  }

  // all weight casts in one launch; wq_a and wkv_a concatenated into w1_b
  {
    const int n0 = (QLORA * HIDDEN) / 4;
    const int n1 = ((QCKN - QLORA) * HIDDEN) / 4;
    const int n2 = (QN * QLORA) / 4;
    const int n3 = (KVN * KVLORA) / 4;
    const int n4s = (HIDDEN * NHEADS * VD) / 4;
    const int tot = n0 + n1 + n2 + n3 + n4s;
    cvt_multi<<<(tot + 255) / 256, 256, 0, stream>>>(
        wq_a, w1_b, n0,
        wkv_a, w1_b + (size_t)QLORA * HIDDEN, n1,
        wq_b, wqb_b, n2,
        wkv_b, wkvb_b, n3,
        wo, wo_b, n4s);
  }

  rmsnorm_k<<<S_LEN, 256, 0, stream>>>(hs, HIDDEN, HIDDEN, ln_w, h_b, HIDDEN);

  // [qa|ckv] = h @ [wq_a;wkv_a]^T   (N=2112, split-K x4 -> 1088 blocks, klen=1280)
  gemm_nt<true, true><<<dim3(16, 17, 4), 256, 0, stream>>>(
      h_b, w1_b, qa_ckv, S_LEN, QCKN, HIDDEN, HIDDEN / 4);

  rmsnorm_k<<<S_LEN, 256, 0, stream>>>(qa_ckv, QCKN, QLORA, q_a_ln, qa_n, QLORA);
  rmsnorm_k<<<S_LEN, 256, 0, stream>>>(qa_ckv + QLORA, QCKN, KVLORA, kv_a_ln, ckv_n, KVLORA);

  // q = qa_n @ wq_b^T   (split-K x2 -> 768 blocks, klen=768)
  gemm_nt<false, true><<<dim3(16, QN / 128, 2), 256, 0, stream>>>(
      qa_n, wqb_b, q_f, S_LEN, QN, QLORA, QLORA / 2);
  // kv = ckv_n @ wkv_b^T  (512 blocks, klen=512)
  gemm_nt<false, false><<<dim3(16, KVN / 128, 1), 256, 0, stream>>>(
      ckv_n, wkvb_b, kv_f, S_LEN, KVN, KVLORA, KVLORA);

  rope_assemble_k<<<S_LEN, 256, 0, stream>>>(q_f, qa_ckv, kv_f, pos, out_k, q_bf, k_bf);
  v_transpose_k<<<dim3(NHEADS, S_LEN / 32, VD / 32), 256, 0, stream>>>(kv_f, out_v, vt_bf);

  attn_k<<<dim3(S_LEN / 64, NHEADS), 256, 0, stream>>>(q_bf, k_bf, vt_bf, attn_b);

  // out_hidden (+)= attn @ wo^T  (split-K x2 -> 1280 blocks, klen=1024; residual pre-stored)
  gemm_nt<false, true><<<dim3(16, HIDDEN / 128, 2), 256, 0, stream>>>(
      attn_b, wo_b, out_hidden, S_LEN, HIDDEN, NHEADS * VD, (NHEADS * VD) / 2);

  (void)in_sizes; (void)n_in; (void)out_size; (void)ws_size;
}

// Round 6
// 594.165 us; speedup vs baseline: 1.0563x; 1.0563x over previous
//
#include <hip/hip_runtime.h>
#include <hip/hip_bf16.h>

typedef __hip_bfloat16 bf16;
typedef __attribute__((ext_vector_type(8))) short bf16x8;
typedef __attribute__((ext_vector_type(4))) float f32x4;

#define S_LEN   2048
#define HIDDEN  5120
#define NHEADS  16
#define QLORA   1536
#define KVLORA  512
#define QKD     192
#define VD      128
#define QN      (NHEADS*QKD)          /* 3072 */
#define KVN     (NHEADS*(128+VD))     /* 4096 */
#define QCKN    2112                  /* 1536 qa | 512 ckv | 64 kpe */
#define SM_SCALE 0.07216878364870322f /* 192^-0.5 */

__device__ __forceinline__ f32x4 mfma16(bf16x8 a, bf16x8 b, f32x4 c) {
  return __builtin_amdgcn_mfma_f32_16x16x32_bf16(a, b, c, 0, 0, 0);
}
__device__ __forceinline__ void g2l16(const void* g, void* l) {
  __builtin_amdgcn_global_load_lds((const __attribute__((address_space(1))) void*)g,
                                   (__attribute__((address_space(3))) void*)l, 16, 0, 0);
}
__device__ __forceinline__ bf16x8 ld8(const bf16* p) { return *(const bf16x8*)p; }

// -------- init: zero split-K accumulators ----------
__global__ void init_k(float4* __restrict__ qa_ckv, int n_qa,
                       float4* __restrict__ q_f, int n_q)
{
  int i = blockIdx.x * 256 + threadIdx.x;
  if (i < n_qa) { qa_ckv[i] = (float4){0.f, 0.f, 0.f, 0.f}; return; }
  if ((i -= n_qa) < n_q) q_f[i] = (float4){0.f, 0.f, 0.f, 0.f};
}

// ---------------- fused fp32 -> bf16 cast over 5 weight segments ----------------
__global__ void cvt_multi(const float* s0, bf16* d0, int n0,
                          const float* s1, bf16* d1, int n1,
                          const float* s2, bf16* d2, int n2,
                          const float* s3, bf16* d3, int n3,
                          const float* s4, bf16* d4, int n4s)
{
  int i = blockIdx.x * 256 + threadIdx.x;
  const float* s; bf16* d;
  if (i < n0) { s = s0; d = d0; }
  else if ((i -= n0) < n1) { s = s1; d = d1; }
  else if ((i -= n1) < n2) { s = s2; d = d2; }
  else if ((i -= n2) < n3) { s = s3; d = d3; }
  else if ((i -= n3) < n4s) { s = s4; d = d4; }
  else return;
  const float4 v = ((const float4*)s)[i];
  union { bf16 b[4]; unsigned long long u; } pk;
  pk.b[0] = __float2bfloat16(v.x);
  pk.b[1] = __float2bfloat16(v.y);
  pk.b[2] = __float2bfloat16(v.z);
  pk.b[3] = __float2bfloat16(v.w);
  *(unsigned long long*)(d + (size_t)i * 4) = pk.u;
}

// ---------------- RMSNorm (fp32 in, bf16 out), one block per row ----------------
__global__ void rmsnorm_k(const float* __restrict__ in, int istride, int C,
                          const float* __restrict__ w,
                          bf16* __restrict__ out, int ostride)
{
  const int row = blockIdx.x;
  const float* x = in + (size_t)row * istride;
  float ss = 0.f;
  for (int c = threadIdx.x; c < C; c += 256) { float v = x[c]; ss += v * v; }
  #pragma unroll
  for (int m = 32; m >= 1; m >>= 1) ss += __shfl_xor(ss, m, 64);
  __shared__ float red[4];
  if ((threadIdx.x & 63) == 0) red[threadIdx.x >> 6] = ss;
  __syncthreads();
  ss = red[0] + red[1] + red[2] + red[3];
  const float sc = rsqrtf(ss / (float)C + 1e-6f);
  bf16* o = out + (size_t)row * ostride;
  for (int c = threadIdx.x; c < C; c += 256)
    o[c] = __float2bfloat16(x[c] * sc * w[c]);
}

// ---- fused dual RMSNorm: rows 0..S-1 -> qa (C=1536), rows S..2S-1 -> ckv (C=512)
__global__ void rmsnorm2_k(const float* __restrict__ qackv,
                           const float* __restrict__ wq, const float* __restrict__ wk,
                           bf16* __restrict__ qa_n, bf16* __restrict__ ckv_n)
{
  const int r = blockIdx.x;
  const bool is_q = r < S_LEN;
  const int row = is_q ? r : r - S_LEN;
  const int C = is_q ? QLORA : KVLORA;
  const float* x = qackv + (size_t)row * QCKN + (is_q ? 0 : QLORA);
  const float* w = is_q ? wq : wk;
  bf16* o = (is_q ? qa_n + (size_t)row * QLORA : ckv_n + (size_t)row * KVLORA);
  float ss = 0.f;
  for (int c = threadIdx.x; c < C; c += 256) { float v = x[c]; ss += v * v; }
  #pragma unroll
  for (int m = 32; m >= 1; m >>= 1) ss += __shfl_xor(ss, m, 64);
  __shared__ float red[4];
  if ((threadIdx.x & 63) == 0) red[threadIdx.x >> 6] = ss;
  __syncthreads();
  ss = red[0] + red[1] + red[2] + red[3];
  const float sc = rsqrtf(ss / (float)C + 1e-6f);
  for (int c = threadIdx.x; c < C; c += 256)
    o[c] = __float2bfloat16(x[c] * sc * w[c]);
}

// ---------------- NT GEMM, BK=64: C[M,N] (+)= A[M,K]*Bt[N,K]^T over K-chunk ----
// 128x128 tile, BK=64, 4 waves each 64x64, global_load_lds width 16. LDS 32 KB.
// launch_bounds(256,4): 4 blocks/CU co-resident (VGPR 56 + AGPR 64 = 120 <= 128
// cap) -> barrier vmcnt(0) drains hidden by other blocks' MFMA.
template<bool RESID, bool CLAMPN, bool ATOMIC>
__global__ __launch_bounds__(256, 4)
void gemm_nt(const bf16* __restrict__ A, const bf16* __restrict__ Bt,
             float* __restrict__ C, int M, int N, int lda, int klen,
             const float* __restrict__ resid, float rscale)
{
  __shared__ bf16 As[2 * 128 * 32];   // chunk-major: [c][row][32]
  __shared__ bf16 Bs[2 * 128 * 32];
  const int tid = threadIdx.x;
  const int wave = tid >> 6;
  const int lane = tid & 63;
  const int l15 = lane & 15, quad = lane >> 4;
  const int bm = blockIdx.x * 128, bn = blockIdx.y * 128;
  const int kbase = blockIdx.z * klen;
  const int wm = (wave >> 1) * 64, wn = (wave & 1) * 64;

  const int srow = tid >> 2;        // 0..63
  const int scol = (tid & 3) * 8;   // 0,8,16,24
  const bf16* Ag0 = A + (size_t)(bm + srow) * lda + kbase + scol;
  const bf16* Ag1 = A + (size_t)(bm + 64 + srow) * lda + kbase + scol;
  int bn0 = bn + srow, bn1 = bn + 64 + srow;
  if (CLAMPN) { bn0 = min(bn0, N - 1); bn1 = min(bn1, N - 1); }
  const bf16* Bg0 = Bt + (size_t)bn0 * lda + kbase + scol;
  const bf16* Bg1 = Bt + (size_t)bn1 * lda + kbase + scol;

  char* AsW = (char*)As + wave * 1024;
  char* BsW = (char*)Bs + wave * 1024;

  f32x4 acc[4][4];
  #pragma unroll
  for (int i = 0; i < 4; i++)
    #pragma unroll
    for (int j = 0; j < 4; j++) acc[i][j] = (f32x4){0.f, 0.f, 0.f, 0.f};

  const int nk = klen >> 6;
  for (int kt = 0; kt < nk; ++kt) {
    const int k0 = kt << 6;
    #pragma unroll
    for (int c = 0; c < 2; ++c) {
      g2l16(Ag0 + k0 + c * 32, AsW + c * 8192);
      g2l16(Ag1 + k0 + c * 32, AsW + c * 8192 + 4096);
      g2l16(Bg0 + k0 + c * 32, BsW + c * 8192);
      g2l16(Bg1 + k0 + c * 32, BsW + c * 8192 + 4096);
    }
    __syncthreads();
    #pragma unroll
    for (int c = 0; c < 2; ++c) {
      bf16x8 af[4], bfr[4];
      #pragma unroll
      for (int i = 0; i < 4; i++)
        af[i] = ld8(As + c * 4096 + (wm + i * 16 + l15) * 32 + quad * 8);
      #pragma unroll
      for (int j = 0; j < 4; j++)
        bfr[j] = ld8(Bs + c * 4096 + (wn + j * 16 + l15) * 32 + quad * 8);
      #pragma unroll
      for (int i = 0; i < 4; i++)
        #pragma unroll
        for (int j = 0; j < 4; j++)
          acc[i][j] = mfma16(af[i], bfr[j], acc[i][j]);
    }
    __syncthreads();
  }

  #pragma unroll
  for (int i = 0; i < 4; i++)
    #pragma unroll
    for (int j = 0; j < 4; j++) {
      const int row = bm + wm + i * 16 + quad * 4;
      const int col = bn + wn + j * 16 + l15;
      if (!CLAMPN || col < N) {
        #pragma unroll
        for (int r = 0; r < 4; r++) {
          float v = acc[i][j][r];
          const size_t idx = (size_t)(row + r) * N + col;
          if (RESID) v += resid[idx] * rscale;
          if (ATOMIC) unsafeAtomicAdd(&C[idx], v);
          else        C[idx] = v;
        }
      }
    }
}

// ---------------- RoPE + assemble q/k (bf16 for attn, fp32 k out) ----------------
__global__ void rope_assemble_k(
    const float* __restrict__ q,      // [S, 3072]
    const float* __restrict__ qackv,  // [S, 2112] (kpe at col 2048)
    const float* __restrict__ kv,     // [S, 4096]
    const int*   __restrict__ pos,    // [S]
    float* __restrict__ k_out,        // [16,S,192]
    bf16*  __restrict__ q_bf,         // [16,S,192]
    bf16*  __restrict__ k_bf)         // [16,S,192]
{
  const int s = blockIdx.x;
  const int t = threadIdx.x;
  __shared__ float cs[32], sn[32], kpe[64];
  const float p = (float)pos[s];
  if (t < 32) {
    const float inv = powf(10000.0f, -((float)(2 * t)) / 64.0f);
    const float f = p * inv;
    float si, c;
    sincosf(f, &si, &c);
    cs[t] = c; sn[t] = si;
    const float r0v = qackv[(size_t)s * QCKN + 2048 + 2 * t];
    const float r1v = qackv[(size_t)s * QCKN + 2048 + 2 * t + 1];
    kpe[t]      = r0v * c - r1v * si;
    kpe[32 + t] = r1v * c + r0v * si;
  }
  __syncthreads();
  for (int i = t; i < NHEADS * 128; i += 256) {
    const int h = i >> 7, d = i & 127;
    const size_t o = ((size_t)h * S_LEN + s) * QKD + d;
    const float kn = kv[(size_t)s * KVN + h * 256 + d];
    k_out[o] = kn;
    k_bf[o] = __float2bfloat16(kn);
    q_bf[o] = __float2bfloat16(q[(size_t)s * QN + h * QKD + d]);
  }
  for (int i = t; i < NHEADS * 32; i += 256) {
    const int h = i >> 5, jj = i & 31;
    const float r0v = q[(size_t)s * QN + h * QKD + 128 + 2 * jj];
    const float r1v = q[(size_t)s * QN + h * QKD + 128 + 2 * jj + 1];
    const float c = cs[jj], si = sn[jj];
    const size_t o = ((size_t)h * S_LEN + s) * QKD + 128;
    q_bf[o + jj]      = __float2bfloat16(r0v * c - r1v * si);
    q_bf[o + 32 + jj] = __float2bfloat16(r1v * c + r0v * si);
  }
  for (int i = t; i < NHEADS * 64; i += 256) {
    const int h = i >> 6, jj = i & 63;
    const float v = kpe[jj];
    const size_t o = ((size_t)h * S_LEN + s) * QKD + 128 + jj;
    k_out[o] = v;
    k_bf[o] = __float2bfloat16(v);
  }
}

// ---------------- V: fp32 out + bf16 transpose [16][128][2048] ----------------
__global__ void v_transpose_k(const float* __restrict__ kv,
                              float* __restrict__ v_out,
                              bf16* __restrict__ vt_bf)
{
  const int h = blockIdx.x, st = blockIdx.y, dt = blockIdx.z;
  __shared__ float tile[32][33];
  const int tx = threadIdx.x & 31;
  const int ty = (threadIdx.x >> 5) * 4;
  const int s0 = st * 32, d0 = dt * 32;
  #pragma unroll
  for (int r = 0; r < 4; r++) {
    const int sl = ty + r;
    const float v = kv[(size_t)(s0 + sl) * KVN + h * 256 + 128 + d0 + tx];
    v_out[((size_t)h * S_LEN + s0 + sl) * VD + d0 + tx] = v;
    tile[sl][tx] = v;
  }
  __syncthreads();
  #pragma unroll
  for (int r = 0; r < 4; r++) {
    const int dl = ty + r;
    vt_bf[((size_t)h * VD + d0 + dl) * S_LEN + s0 + tx] = __float2bfloat16(tile[tx][dl]);
  }
}

// ---------------- causal flash attention (v4, unchanged) ----------------
__global__ __launch_bounds__(256, 3)
void attn_k(const bf16* __restrict__ qb, const bf16* __restrict__ kb,
            const bf16* __restrict__ vt, bf16* __restrict__ aout)
{
  const int head = blockIdx.y;
  const int qt = (head < 8) ? blockIdx.x : (gridDim.x - 1 - blockIdx.x);
  const int wave = threadIdx.x >> 6, lane = threadIdx.x & 63;
  const int l15 = lane & 15, quad = lane >> 4;
  const int r0 = qt * 64 + wave * 16;

  const bf16* qh = qb + (size_t)head * S_LEN * QKD;
  const bf16* kh = kb + (size_t)head * S_LEN * QKD;
  const bf16* vh = vt + (size_t)head * VD * S_LEN;

  __shared__ bf16 Ks[6 * 64 * 32];
  __shared__ bf16 Vs[128 * 72];
  __shared__ bf16 Plds[4][16][72];

  const int tid = threadIdx.x;
  const int srow = wave * 16 + (lane >> 2);
  const int scol = (lane & 3) * 8;
  const bf16* ksrc = kh + (size_t)srow * QKD + scol;
  bf16* kdst = Ks + srow * 32 + scol;
  const int vrow = tid >> 1;
  const int vcol = (tid & 1) * 32;
  const bf16* vsrc = vh + (size_t)vrow * S_LEN + vcol;
  bf16* vdst = Vs + vrow * 72 + vcol;

  bf16x8 qf[6];
  #pragma unroll
  for (int c = 0; c < 6; ++c)
    qf[c] = ld8(qh + (size_t)(r0 + l15) * QKD + c * 32 + quad * 8);

  f32x4 O[8];
  #pragma unroll
  for (int d = 0; d < 8; ++d) O[d] = (f32x4){0.f, 0.f, 0.f, 0.f};
  float mrow[4] = {-1e30f, -1e30f, -1e30f, -1e30f};
  float lrow[4] = {0.f, 0.f, 0.f, 0.f};

  bf16x8 kreg[6], vreg[4];
  #pragma unroll
  for (int c = 0; c < 6; ++c) kreg[c] = ld8(ksrc + c * 32);
  #pragma unroll
  for (int c = 0; c < 4; ++c) vreg[c] = ld8(vsrc + c * 8);

  for (int j = 0; j <= qt; ++j) {
    __syncthreads();
    #pragma unroll
    for (int c = 0; c < 6; ++c) *(bf16x8*)(kdst + c * 2048) = kreg[c];
    #pragma unroll
    for (int c = 0; c < 4; ++c) *(bf16x8*)(vdst + c * 8) = vreg[c];
    __syncthreads();
    if (j < qt) {
      const bf16* src = ksrc + (size_t)(j + 1) * 64 * QKD;
      #pragma unroll
      for (int c = 0; c < 6; ++c) kreg[c] = ld8(src + c * 32);
      const bf16* vs2 = vsrc + (size_t)(j + 1) * 64;
      #pragma unroll
      for (int c = 0; c < 4; ++c) vreg[c] = ld8(vs2 + c * 8);
    }
    const int kc = j * 64;

    f32x4 S[4];
    #pragma unroll
    for (int nt = 0; nt < 4; ++nt) S[nt] = (f32x4){0.f, 0.f, 0.f, 0.f};
    #pragma unroll
    for (int c = 0; c < 6; ++c) {
      #pragma unroll
      for (int nt = 0; nt < 4; ++nt) {
        const bf16x8 kf = ld8(Ks + c * 2048 + (nt * 16 + l15) * 32 + quad * 8);
        S[nt] = mfma16(qf[c], kf, S[nt]);
      }
    }

    float mnew[4] = {-1e30f, -1e30f, -1e30f, -1e30f};
    if (j == qt) {
      #pragma unroll
      for (int nt = 0; nt < 4; ++nt) {
        const int col = kc + nt * 16 + l15;
        #pragma unroll
        for (int r = 0; r < 4; r++) {
          const int row = r0 + quad * 4 + r;
          const float v = (col <= row) ? S[nt][r] * SM_SCALE : -1e30f;
          S[nt][r] = v;
          mnew[r] = fmaxf(mnew[r], v);
        }
      }
    } else {
      #pragma unroll
      for (int nt = 0; nt < 4; ++nt)
        #pragma unroll
        for (int r = 0; r < 4; r++) {
          const float v = S[nt][r] * SM_SCALE;
          S[nt][r] = v;
          mnew[r] = fmaxf(mnew[r], v);
        }
    }
    #pragma unroll
    for (int m = 8; m >= 1; m >>= 1)
      #pragma unroll
      for (int r = 0; r < 4; r++)
        mnew[r] = fmaxf(mnew[r], __shfl_xor(mnew[r], m, 64));
    float alpha[4], ladd[4] = {0.f, 0.f, 0.f, 0.f};
    #pragma unroll
    for (int r = 0; r < 4; r++) {
      const float mi = fmaxf(mrow[r], mnew[r]);
      alpha[r] = __expf(mrow[r] - mi);
      mrow[r] = mi;
    }
    #pragma unroll
    for (int nt = 0; nt < 4; ++nt)
      #pragma unroll
      for (int r = 0; r < 4; r++) {
        const float pv = __expf(S[nt][r] - mrow[r]);
        S[nt][r] = pv;
        ladd[r] += pv;
      }
    #pragma unroll
    for (int m = 8; m >= 1; m >>= 1)
      #pragma unroll
      for (int r = 0; r < 4; r++) ladd[r] += __shfl_xor(ladd[r], m, 64);
    #pragma unroll
    for (int r = 0; r < 4; r++) lrow[r] = lrow[r] * alpha[r] + ladd[r];
    #pragma unroll
    for (int d = 0; d < 8; ++d)
      #pragma unroll
      for (int r = 0; r < 4; r++) O[d][r] *= alpha[r];

    #pragma unroll
    for (int nt = 0; nt < 4; ++nt)
      #pragma unroll
      for (int r = 0; r < 4; r++)
        Plds[wave][quad * 4 + r][nt * 16 + l15] = __float2bfloat16(S[nt][r]);

    #pragma unroll
    for (int kt = 0; kt < 2; ++kt) {
      const bf16x8 pf = ld8(&Plds[wave][l15][kt * 32 + quad * 8]);
      #pragma unroll
      for (int dt = 0; dt < 8; ++dt) {
        const bf16x8 vf = ld8(Vs + (dt * 16 + l15) * 72 + kt * 32 + quad * 8);
        O[dt] = mfma16(pf, vf, O[dt]);
      }
    }
  }

  #pragma unroll
  for (int dt = 0; dt < 8; ++dt) {
    const int col = head * VD + dt * 16 + l15;
    #pragma unroll
    for (int r = 0; r < 4; r++) {
      const int row = r0 + quad * 4 + r;
      aout[(size_t)row * (NHEADS * VD) + col] = __float2bfloat16(O[dt][r] / lrow[r]);
    }
  }
}

// ---------------- host orchestration ----------------
extern "C" void kernel_launch(void* const* d_in, const int* in_sizes, int n_in,
                              void* d_out, int out_size, void* d_ws, size_t ws_size,
                              hipStream_t stream)
{
  const float* hs      = (const float*)d_in[0];
  const int*   pos     = (const int*)  d_in[1];
  const float* ln_w    = (const float*)d_in[3];
  const float* wq_a    = (const float*)d_in[4];
  const float* q_a_ln  = (const float*)d_in[5];
  const float* wq_b    = (const float*)d_in[6];
  const float* wkv_a   = (const float*)d_in[7];
  const float* kv_a_ln = (const float*)d_in[8];
  const float* wkv_b   = (const float*)d_in[9];
  const float* wo      = (const float*)d_in[10];

  float* out_hidden = (float*)d_out;
  float* out_k = out_hidden + (size_t)S_LEN * HIDDEN;
  float* out_v = out_k + (size_t)NHEADS * S_LEN * QKD;

  char* ws = (char*)d_ws;
  size_t off = 0;
  auto alloc = [&](size_t bytes) { char* p = ws + off; off += (bytes + 255) & ~255ULL; return p; };

  bf16* h_b     = (bf16*)alloc((size_t)S_LEN * HIDDEN * 2);
  bf16* w1_b    = (bf16*)alloc((size_t)QCKN * HIDDEN * 2);
  bf16* wqb_b   = (bf16*)alloc((size_t)QN * QLORA * 2);
  bf16* wkvb_b  = (bf16*)alloc((size_t)KVN * KVLORA * 2);
  bf16* wo_b    = (bf16*)alloc((size_t)HIDDEN * (NHEADS * VD) * 2);
  float* qa_ckv = (float*)alloc((size_t)S_LEN * QCKN * 4);
  float* q_f    = (float*)alloc((size_t)S_LEN * QN * 4);
  bf16* qa_n    = (bf16*)alloc((size_t)S_LEN * QLORA * 2);
  bf16* ckv_n   = (bf16*)alloc((size_t)S_LEN * KVLORA * 2);
  float* kv_f   = (float*)alloc((size_t)S_LEN * KVN * 4);
  bf16* q_bf    = (bf16*)alloc((size_t)NHEADS * S_LEN * QKD * 2);
  bf16* k_bf    = (bf16*)alloc((size_t)NHEADS * S_LEN * QKD * 2);
  bf16* vt_bf   = (bf16*)alloc((size_t)NHEADS * VD * S_LEN * 2);
  bf16* attn_b  = (bf16*)alloc((size_t)S_LEN * (NHEADS * VD) * 2);

  {
    const int n_qa = (int)((size_t)S_LEN * QCKN / 4);
    const int n_q  = (int)((size_t)S_LEN * QN / 4);
    const int tot = n_qa + n_q;
    init_k<<<(tot + 255) / 256, 256, 0, stream>>>(
        (float4*)qa_ckv, n_qa, (float4*)q_f, n_q);
  }

  {
    const int n0 = (QLORA * HIDDEN) / 4;
    const int n1 = ((QCKN - QLORA) * HIDDEN) / 4;
    const int n2 = (QN * QLORA) / 4;
    const int n3 = (KVN * KVLORA) / 4;
    const int n4s = (HIDDEN * NHEADS * VD) / 4;
    const int tot = n0 + n1 + n2 + n3 + n4s;
    cvt_multi<<<(tot + 255) / 256, 256, 0, stream>>>(
        wq_a, w1_b, n0,
        wkv_a, w1_b + (size_t)QLORA * HIDDEN, n1,
        wq_b, wqb_b, n2,
        wkv_b, wkvb_b, n3,
        wo, wo_b, n4s);
  }

  rmsnorm_k<<<S_LEN, 256, 0, stream>>>(hs, HIDDEN, HIDDEN, ln_w, h_b, HIDDEN);

  // [qa|ckv] = h @ [wq_a;wkv_a]^T   (split-K x4 -> 1088 blocks, klen=1280)
  gemm_nt<false, true, true><<<dim3(16, 17, 4), 256, 0, stream>>>(
      h_b, w1_b, qa_ckv, S_LEN, QCKN, HIDDEN, HIDDEN / 4, nullptr, 0.f);

  // fused dual rmsnorm (qa rows | ckv rows) in one launch
  rmsnorm2_k<<<2 * S_LEN, 256, 0, stream>>>(qa_ckv, q_a_ln, kv_a_ln, qa_n, ckv_n);

  // q = qa_n @ wq_b^T   (split-K x2 -> 768 blocks, klen=768)
  gemm_nt<false, false, true><<<dim3(16, QN / 128, 2), 256, 0, stream>>>(
      qa_n, wqb_b, q_f, S_LEN, QN, QLORA, QLORA / 2, nullptr, 0.f);
  // kv = ckv_n @ wkv_b^T  (512 blocks, klen=512)
  gemm_nt<false, false, false><<<dim3(16, KVN / 128, 1), 256, 0, stream>>>(
      ckv_n, wkvb_b, kv_f, S_LEN, KVN, KVLORA, KVLORA, nullptr, 0.f);

  rope_assemble_k<<<S_LEN, 256, 0, stream>>>(q_f, qa_ckv, kv_f, pos, out_k, q_bf, k_bf);
  v_transpose_k<<<dim3(NHEADS, S_LEN / 32, VD / 32), 256, 0, stream>>>(kv_f, out_v, vt_bf);

  attn_k<<<dim3(S_LEN / 64, NHEADS), 256, 0, stream>>>(q_bf, k_bf, vt_bf, attn_b);

  // out = attn @ wo^T + hs*0.125  (640 blocks, klen=2048, no split / no atomics)
  gemm_nt<true, false, false><<<dim3(16, HIDDEN / 128, 1), 256, 0, stream>>>(
      attn_b, wo_b, out_hidden, S_LEN, HIDDEN, NHEADS * VD, NHEADS * VD, hs, 0.125f);

  (void)in_sizes; (void)n_in; (void)out_size; (void)ws_size;
}